// Round 6
// baseline (154.991 us; speedup 1.0000x reference)
//
#include <hip/hip_runtime.h>

// ---------------------------------------------------------------------------
// DCT-conv:  out = IDCT_H( circconv_W( DCT_H(x), DCT_H(pad(w)) ) summed over ci ) + bias
// B=8, c_in=64, c_out=128, H=W=128, kh=kw=5.
//
// Pipeline (all fp16 storage, fp32 MFMA accumulate).  R6: all GEMM kernels
// split to 2x finer grids (16 KB LDS tiles) -- R3 counters showed the old
// 1024-wg kernels were latency-bound (Occupancy 25%, HBM 32%, all pipes idle):
// grid gave only 4 wgs/CU so stage-phase global latency was never hidden.
//   k_prep : D,M matrices + WD [k][s=10][co=128][kk=32]          (256 wgs)
//   k_dctH : xd[k][b][ci][w] = D @ x[b][ci]        (1024 wgs, w-halves)
//   k_conv : y2[b][co][k][w] = sum WD * xd-shifted (2048 wgs, co-halves,
//            barrier-free K-loop, WD A-frags from L2, reg prefetch)
//   k_idct : out[b][co][h][w] = M @ y2 + bias      (2048 wgs, w-halves)
// ---------------------------------------------------------------------------

using half8v = __attribute__((ext_vector_type(8))) _Float16;
using half4v = __attribute__((ext_vector_type(4))) _Float16;
using f32x4  = __attribute__((ext_vector_type(4))) float;

#define PI_F 3.14159265358979323846f

// Bank-spread function: distinct over both n-stride-1 (reads) and n-stride-8 (writes).
__device__ __forceinline__ int swz(int n) { return (n ^ (n >> 3)) & 7; }

// Swizzled LDS offset for [n][K] layouts (8-half chunks; XOR 3-bit swz into chunk idx).
__device__ __forceinline__ int sw_off(int n, int k, int K) {
    int c = k >> 3;
    return n * K + (((c ^ swz(n)) << 3) | (k & 7));
}

// ---------------------------------------------------------------------------
// k_prep: WD[((k*10+s)*128+co)*32+kk] = sum_i 2cos(pi(2i+1)k/256) * w[co][ci][i][j]
//   with j = s>>1, ci = (s&1)*32 + kk.  Also fills D/M (64 entries per wg).
__global__ __launch_bounds__(256) void k_prep(const float* __restrict__ w,
                                              _Float16* __restrict__ WD,
                                              _Float16* __restrict__ D,
                                              _Float16* __restrict__ M) {
    __shared__ float lw[1600];      // w[co][ci][i][j]  (64*5*5)
    __shared__ float lcos[320];     // 2*cos(pi(2i+1)(k0+kl)/256), [kl][i]
    int co = blockIdx.x >> 1, k0 = (blockIdx.x & 1) << 6;
    int tid = threadIdx.x;

    for (int e = tid; e < 1600; e += 256) lw[e] = w[co * 1600 + e];
    for (int e = tid; e < 320; e += 256) {
        int kl = e / 5, i = e - kl * 5;
        lcos[e] = 2.0f * cosf(PI_F * (float)((2 * i + 1) * (k0 + kl)) * (1.0f / 256.0f));
    }
    // D/M matrices: 256 wgs x 64 entries = all 16384 (k,h) pairs.
    if (tid < 64) {
        int g = blockIdx.x * 64 + tid;
        int k = g >> 7, h = g & 127;
        float ang = PI_F * (float)((2 * h + 1) * k) * (1.0f / 256.0f);
        float c = cosf(ang);
        D[k * 128 + h] = (_Float16)(2.0f * c);
        float wk = (k == 0) ? 0.5f : 1.0f;
        M[h * 128 + k] = (_Float16)(c * wk * (1.0f / 256.0f));
    }
    __syncthreads();

    for (int e = tid; e < 20480; e += 256) {
        int kk = e & 31, rest = e >> 5;
        int s = rest % 10, kl = rest / 10;
        int j = s >> 1, ci = ((s & 1) << 5) + kk;
        const float* wp = &lw[ci * 25 + j];
        const float* cp = &lcos[kl * 5];
        float acc = 0.f;
#pragma unroll
        for (int i = 0; i < 5; ++i) acc += cp[i] * wp[i * 5];
        WD[(((long)(k0 + kl) * 10 + s) * 128 + co) * 32 + kk] = (_Float16)acc;
    }
}

// ---------------------------------------------------------------------------
// GEMM core, half-width tile: A [128m][K=128] from global (L1/L2-hot),
// B [n=64][K=128] from swizzled LDS.  Output 128m x 64n: wm halves m,
// wn halves n (32 each), mt=4, nt=2.
__device__ __forceinline__ void gemm128x64_gA(const _Float16* __restrict__ gA,
                                              const _Float16* lB,
                                              f32x4 acc[4][2], int tid) {
    int lane = tid & 63, ln = lane & 15, q = lane >> 4;
    int wave = tid >> 6, wm = wave >> 1, wn = wave & 1;
#pragma unroll
    for (int s = 0; s < 4; ++s) {
        half8v af[4], bf[2];
#pragma unroll
        for (int mt = 0; mt < 4; ++mt) {
            int m = wm * 64 + mt * 16 + ln;
            af[mt] = *(const half8v*)(&gA[m * 128 + (s * 4 + q) * 8]);
        }
#pragma unroll
        for (int nt = 0; nt < 2; ++nt) {
            int n = wn * 32 + nt * 16 + ln;
            bf[nt] = *(const half8v*)(&lB[n * 128 + (((s * 4 + q) ^ swz(n)) << 3)]);
        }
#pragma unroll
        for (int mt = 0; mt < 4; ++mt)
#pragma unroll
            for (int nt = 0; nt < 2; ++nt)
                acc[mt][nt] = __builtin_amdgcn_mfma_f32_16x16x32_f16(af[mt], bf[nt], acc[mt][nt], 0, 0, 0);
    }
}

// Transpose-stage fp16 rows [K=128][64 w] (row k at src + k*row_stride) into
// swizzled LDS [n=w(64)][K=128].  256 threads, one 4x8 block each.
__device__ __forceinline__ void stage_transB64(const _Float16* __restrict__ src, int row_stride,
                                               _Float16* l, int tid) {
    int kb = tid >> 3, wb = tid & 7;
    int k0 = kb * 4, w0 = wb * 8;
    half8v r0 = *(const half8v*)(&src[(k0 + 0) * row_stride + w0]);
    half8v r1 = *(const half8v*)(&src[(k0 + 1) * row_stride + w0]);
    half8v r2 = *(const half8v*)(&src[(k0 + 2) * row_stride + w0]);
    half8v r3 = *(const half8v*)(&src[(k0 + 3) * row_stride + w0]);
#pragma unroll
    for (int dw = 0; dw < 8; ++dw) {
        int n = w0 + dw;
        half4v p = {r0[dw], r1[dw], r2[dw], r3[dw]};
        *(half4v*)(&l[sw_off(n, k0, 128)]) = p;
    }
}

// Transpose-stage fp16 rows [k][128 w] into swizzled LDS [n=w(128)][K=64]
// (conv's xd tile; K=64, 256 blocks).
__device__ __forceinline__ void stage_transB128(const _Float16* __restrict__ src,
                                                _Float16* l, int tid) {
    int kb = tid >> 4, wb = tid & 15;
    int k0 = kb * 4, w0 = wb * 8;
    half8v r0 = *(const half8v*)(&src[(k0 + 0) * 128 + w0]);
    half8v r1 = *(const half8v*)(&src[(k0 + 1) * 128 + w0]);
    half8v r2 = *(const half8v*)(&src[(k0 + 2) * 128 + w0]);
    half8v r3 = *(const half8v*)(&src[(k0 + 3) * 128 + w0]);
#pragma unroll
    for (int dw = 0; dw < 8; ++dw) {
        int n = w0 + dw;
        half4v p = {r0[dw], r1[dw], r2[dw], r3[dw]};
        *(half4v*)(&l[sw_off(n, k0, 64)]) = p;
    }
}

// ---------------------------------------------------------------------------
// Step A: xd[k][b][ci][w] = sum_h D[k][h] * x[b][ci][h][w]   (w-halves)
__global__ __launch_bounds__(256) void k_dctH(const float* __restrict__ x,
                                              const _Float16* __restrict__ Dg,
                                              _Float16* __restrict__ xd) {
    __shared__ __align__(16) _Float16 lB[64 * 128];      // 16 KB
    int b = blockIdx.x >> 7, ci = (blockIdx.x >> 1) & 63, wh = blockIdx.x & 1;
    int w0g = wh * 64;
    int tid = threadIdx.x;

    // Stage x[b][ci][0..128h][w0g..w0g+64) as fp16, transposed+swizzled.
    const float* xs = x + (long)(b * 64 + ci) * 16384 + w0g;
    {
        int kb = tid >> 3, wb = tid & 7;
        int h0 = kb * 4, c0 = wb * 8;
        f32x4 f[4][2];
#pragma unroll
        for (int dh = 0; dh < 4; ++dh) {
            f[dh][0] = *(const f32x4*)(&xs[(h0 + dh) * 128 + c0]);
            f[dh][1] = *(const f32x4*)(&xs[(h0 + dh) * 128 + c0 + 4]);
        }
#pragma unroll
        for (int dw = 0; dw < 8; ++dw) {
            int n = c0 + dw;
            half4v p = {(_Float16)f[0][dw >> 2][dw & 3], (_Float16)f[1][dw >> 2][dw & 3],
                        (_Float16)f[2][dw >> 2][dw & 3], (_Float16)f[3][dw >> 2][dw & 3]};
            *(half4v*)(&lB[sw_off(n, h0, 128)]) = p;
        }
    }
    __syncthreads();

    f32x4 acc[4][2] = {};
    gemm128x64_gA(Dg, lB, acc, tid);

    int lane = tid & 63, ln = lane & 15, q = lane >> 4;
    int wave = tid >> 6, wm = wave >> 1, wn = wave & 1;
#pragma unroll
    for (int mt = 0; mt < 4; ++mt)
#pragma unroll
        for (int nt = 0; nt < 2; ++nt)
#pragma unroll
            for (int r = 0; r < 4; ++r) {
                int kk = wm * 64 + mt * 16 + q * 4 + r;
                int wcol = w0g + wn * 32 + nt * 16 + ln;
                xd[((long)(kk * 8 + b) * 64 + ci) * 128 + wcol] = (_Float16)acc[mt][nt][r];
            }
}

// ---------------------------------------------------------------------------
// Step B: per (k,b,co-half):  y2[b][co][k][w] = sum_{s,kk} WD[k][s][co][kk] * xd[k][b][ci][(w-j)&127]
// Barrier-free K-loop, WD A-frags from global/L2 (the 16 wgs sharing a k-tile
// all have bid == k (mod 8) -> same XCD), register prefetch distance 1.
__global__ __launch_bounds__(256) void k_conv(const _Float16* __restrict__ xd,
                                              const _Float16* __restrict__ WD,
                                              _Float16* __restrict__ y2) {
    __shared__ __align__(16) _Float16 lX[128 * 64];        // [w][ci] swizzled (16 KB)
    int bid = blockIdx.x;
    int k = bid & 127, r2 = bid >> 7;
    int ch = r2 & 1, b = r2 >> 1;
    int tid = threadIdx.x;
    int lane = tid & 63, wave = tid >> 6;

    const _Float16* xs = xd + (long)(k * 8 + b) * 8192;
    stage_transB128(xs, lX, tid);
    __syncthreads();     // the only barrier

    int ln = lane & 15, q = lane >> 4;
    int wm = wave >> 1, wn = wave & 1;
    f32x4 acc[2][4] = {};

    const _Float16* wkb = WD + (long)k * 40960;   // k * 10 * 4096
    int mbase = (ch * 64 + wm * 32 + ln) * 32 + q * 8;   // A-frag offset (+mt*512)

    // Prefetch s=0 A-fragments.
    half8v afn[2];
#pragma unroll
    for (int mt = 0; mt < 2; ++mt)
        afn[mt] = *(const half8v*)(&wkb[mbase + mt * 512]);

    for (int s = 0; s < 10; ++s) {
        half8v af[2];
#pragma unroll
        for (int mt = 0; mt < 2; ++mt) af[mt] = afn[mt];
        if (s < 9) {
            const _Float16* wt = wkb + (s + 1) * 4096;
#pragma unroll
            for (int mt = 0; mt < 2; ++mt)
                afn[mt] = *(const half8v*)(&wt[mbase + mt * 512]);
        }
        int j = s >> 1;
        int cb = (s & 1) << 2;   // ci-chunk base within K=64
        half8v bf[4];
#pragma unroll
        for (int nt = 0; nt < 4; ++nt) {
            int wcol = wn * 64 + nt * 16 + ln;
            int n = (wcol - j) & 127;
            bf[nt] = *(const half8v*)(&lX[n * 64 + (((cb + q) ^ swz(n)) << 3)]);
        }
        __builtin_amdgcn_s_setprio(1);
#pragma unroll
        for (int mt = 0; mt < 2; ++mt)
#pragma unroll
            for (int nt = 0; nt < 4; ++nt)
                acc[mt][nt] = __builtin_amdgcn_mfma_f32_16x16x32_f16(af[mt], bf[nt], acc[mt][nt], 0, 0, 0);
        __builtin_amdgcn_s_setprio(0);
    }

    // y2 layout [b][co][k][w]: idct reads become fully contiguous per (b,co).
    _Float16* yb = y2 + (long)b * 2097152 + k * 128;
#pragma unroll
    for (int mt = 0; mt < 2; ++mt)
#pragma unroll
        for (int nt = 0; nt < 4; ++nt)
#pragma unroll
            for (int r = 0; r < 4; ++r) {
                int co = ch * 64 + wm * 32 + mt * 16 + q * 4 + r;
                int wcol = wn * 64 + nt * 16 + ln;
                yb[(long)co * 16384 + wcol] = (_Float16)acc[mt][nt][r];
            }
}

// ---------------------------------------------------------------------------
// Step C: out[b][co][h][w] = sum_k M[h][k] * y2[b][co][k][w] + bias[co]  (w-halves)
__global__ __launch_bounds__(256) void k_idct(const _Float16* __restrict__ y2,
                                              const _Float16* __restrict__ Mg,
                                              const float* __restrict__ bias,
                                              float* __restrict__ out) {
    __shared__ __align__(16) _Float16 lB[64 * 128];      // 16 KB
    int b = blockIdx.x >> 8, co = (blockIdx.x >> 1) & 127, wh = blockIdx.x & 1;
    int w0g = wh * 64;
    int tid = threadIdx.x;

    // Contiguous-stride [k][w-half] block per (b,co,wh).
    const _Float16* src = y2 + (long)b * 2097152 + (long)co * 16384 + w0g;
    stage_transB64(src, 128, lB, tid);
    __syncthreads();

    f32x4 acc[4][2] = {};
    gemm128x64_gA(Mg, lB, acc, tid);

    float bv = bias[co];
    float* ob = out + ((long)(b * 128 + co)) * 16384 + w0g;
    int lane = tid & 63, ln = lane & 15, q = lane >> 4;
    int wave = tid >> 6, wm = wave >> 1, wn = wave & 1;
#pragma unroll
    for (int mt = 0; mt < 4; ++mt)
#pragma unroll
        for (int nt = 0; nt < 2; ++nt)
#pragma unroll
            for (int r = 0; r < 4; ++r) {
                int h = wm * 64 + mt * 16 + q * 4 + r;
                int wcol = wn * 32 + nt * 16 + ln;
                ob[h * 128 + wcol] = acc[mt][nt][r] + bv;
            }
}

// ---------------------------------------------------------------------------
extern "C" void kernel_launch(void* const* d_in, const int* in_sizes, int n_in,
                              void* d_out, int out_size, void* d_ws, size_t ws_size,
                              hipStream_t stream) {
    const float* x    = (const float*)d_in[0];  // [8][64][128][128]
    const float* w    = (const float*)d_in[1];  // [128][64][5][5]
    const float* bias = (const float*)d_in[2];  // [128]
    float* out = (float*)d_out;                 // [8][128][128][128]

    char* ws = (char*)d_ws;
    _Float16* D  = (_Float16*)(ws);                                  //  32 KB
    _Float16* M  = (_Float16*)(ws + 32768);                          //  32 KB
    _Float16* WD = (_Float16*)(ws + 65536);                          //  10.0 MB
    _Float16* xd = (_Float16*)(ws + 65536 + 10485760);               //  16 MB
    _Float16* y2 = (_Float16*)(ws + 65536 + 10485760 + 16777216);    //  32 MB

    k_prep<<<dim3(256),  dim3(256), 0, stream>>>(w, WD, D, M);
    k_dctH<<<dim3(1024), dim3(256), 0, stream>>>(x, D, xd);
    k_conv<<<dim3(2048), dim3(256), 0, stream>>>(xd, WD, y2);
    k_idct<<<dim3(2048), dim3(256), 0, stream>>>(y2, M, bias, out);
}

// Round 7
// 146.785 us; speedup vs baseline: 1.0559x; 1.0559x over previous
//
#include <hip/hip_runtime.h>

// ---------------------------------------------------------------------------
// DCT-conv:  out = IDCT_H( circconv_W( DCT_H(x), DCT_H(pad(w)) ) summed over ci ) + bias
// B=8, c_in=64, c_out=128, H=W=128, kh=kw=5.
//
// Pipeline (all fp16 storage, fp32 MFMA accumulate).  R7 = R5 base (best,
// 143.5us) + dctH w-half split ONLY (R5 dctH had grid 512 = 2 wgs/CU, the
// worst TLP in the pipeline; R6's bundle of 3 splits regressed -- conv's
// split doubled staging traffic, so conv/idct stay at R5 structure).
//   k_prep : D,M matrices + WD [k][s=10][co=128][kk=32]          (256 wgs)
//   k_dctH : xd[k][b][ci][w] = D @ x[b][ci]        (1024 wgs, w-halves, 16KB)
//   k_conv : y2[b][co][k][w] = sum WD * xd-shifted (1024 wgs, b-major,
//            barrier-free K-loop, WD A-frags from L2, reg prefetch)
//   k_idct : out[b][co][h][w] = M @ y2 + bias      (1024 wgs, contiguous y2)
// ---------------------------------------------------------------------------

using half8v = __attribute__((ext_vector_type(8))) _Float16;
using half4v = __attribute__((ext_vector_type(4))) _Float16;
using f32x4  = __attribute__((ext_vector_type(4))) float;

#define PI_F 3.14159265358979323846f

// Bank-spread function: distinct over both n-stride-1 (reads) and n-stride-8 (writes).
__device__ __forceinline__ int swz(int n) { return (n ^ (n >> 3)) & 7; }

// Swizzled LDS offset for [n][K] layouts (8-half chunks; XOR 3-bit swz into chunk idx).
__device__ __forceinline__ int sw_off(int n, int k, int K) {
    int c = k >> 3;
    return n * K + (((c ^ swz(n)) << 3) | (k & 7));
}

// ---------------------------------------------------------------------------
// k_prep: WD[((k*10+s)*128+co)*32+kk] = sum_i 2cos(pi(2i+1)k/256) * w[co][ci][i][j]
//   with j = s>>1, ci = (s&1)*32 + kk.  Also fills D/M (64 entries per wg).
__global__ __launch_bounds__(256) void k_prep(const float* __restrict__ w,
                                              _Float16* __restrict__ WD,
                                              _Float16* __restrict__ D,
                                              _Float16* __restrict__ M) {
    __shared__ float lw[1600];      // w[co][ci][i][j]  (64*5*5)
    __shared__ float lcos[320];     // 2*cos(pi(2i+1)(k0+kl)/256), [kl][i]
    int co = blockIdx.x >> 1, k0 = (blockIdx.x & 1) << 6;
    int tid = threadIdx.x;

    for (int e = tid; e < 1600; e += 256) lw[e] = w[co * 1600 + e];
    for (int e = tid; e < 320; e += 256) {
        int kl = e / 5, i = e - kl * 5;
        lcos[e] = 2.0f * cosf(PI_F * (float)((2 * i + 1) * (k0 + kl)) * (1.0f / 256.0f));
    }
    // D/M matrices: 256 wgs x 64 entries = all 16384 (k,h) pairs.
    if (tid < 64) {
        int g = blockIdx.x * 64 + tid;
        int k = g >> 7, h = g & 127;
        float ang = PI_F * (float)((2 * h + 1) * k) * (1.0f / 256.0f);
        float c = cosf(ang);
        D[k * 128 + h] = (_Float16)(2.0f * c);
        float wk = (k == 0) ? 0.5f : 1.0f;
        M[h * 128 + k] = (_Float16)(c * wk * (1.0f / 256.0f));
    }
    __syncthreads();

    for (int e = tid; e < 20480; e += 256) {
        int kk = e & 31, rest = e >> 5;
        int s = rest % 10, kl = rest / 10;
        int j = s >> 1, ci = ((s & 1) << 5) + kk;
        const float* wp = &lw[ci * 25 + j];
        const float* cp = &lcos[kl * 5];
        float acc = 0.f;
#pragma unroll
        for (int i = 0; i < 5; ++i) acc += cp[i] * wp[i * 5];
        WD[(((long)(k0 + kl) * 10 + s) * 128 + co) * 32 + kk] = (_Float16)acc;
    }
}

// ---------------------------------------------------------------------------
// GEMM core, full tile: A [128m][K=128] from global (L1/L2-hot), B [n=128][K=128]
// from swizzled LDS.  Output 128x128 over 4 waves (wm x wn halves, 4x4 frags).
__device__ __forceinline__ void gemm128_gA(const _Float16* __restrict__ gA,
                                           const _Float16* lB,
                                           f32x4 acc[4][4], int tid) {
    int lane = tid & 63, ln = lane & 15, q = lane >> 4;
    int wave = tid >> 6, wm = wave >> 1, wn = wave & 1;
#pragma unroll
    for (int s = 0; s < 4; ++s) {
        half8v af[4], bf[4];
#pragma unroll
        for (int mt = 0; mt < 4; ++mt) {
            int m = wm * 64 + mt * 16 + ln;
            af[mt] = *(const half8v*)(&gA[m * 128 + (s * 4 + q) * 8]);
        }
#pragma unroll
        for (int nt = 0; nt < 4; ++nt) {
            int n = wn * 64 + nt * 16 + ln;
            bf[nt] = *(const half8v*)(&lB[n * 128 + (((s * 4 + q) ^ swz(n)) << 3)]);
        }
#pragma unroll
        for (int mt = 0; mt < 4; ++mt)
#pragma unroll
            for (int nt = 0; nt < 4; ++nt)
                acc[mt][nt] = __builtin_amdgcn_mfma_f32_16x16x32_f16(af[mt], bf[nt], acc[mt][nt], 0, 0, 0);
    }
}

// GEMM core, half-width tile: A [128m][K=128] from global, B [n=64][K=128]
// from swizzled LDS.  Output 128m x 64n: wm halves m, wn halves n (32 each).
__device__ __forceinline__ void gemm128x64_gA(const _Float16* __restrict__ gA,
                                              const _Float16* lB,
                                              f32x4 acc[4][2], int tid) {
    int lane = tid & 63, ln = lane & 15, q = lane >> 4;
    int wave = tid >> 6, wm = wave >> 1, wn = wave & 1;
#pragma unroll
    for (int s = 0; s < 4; ++s) {
        half8v af[4], bf[2];
#pragma unroll
        for (int mt = 0; mt < 4; ++mt) {
            int m = wm * 64 + mt * 16 + ln;
            af[mt] = *(const half8v*)(&gA[m * 128 + (s * 4 + q) * 8]);
        }
#pragma unroll
        for (int nt = 0; nt < 2; ++nt) {
            int n = wn * 32 + nt * 16 + ln;
            bf[nt] = *(const half8v*)(&lB[n * 128 + (((s * 4 + q) ^ swz(n)) << 3)]);
        }
#pragma unroll
        for (int mt = 0; mt < 4; ++mt)
#pragma unroll
            for (int nt = 0; nt < 2; ++nt)
                acc[mt][nt] = __builtin_amdgcn_mfma_f32_16x16x32_f16(af[mt], bf[nt], acc[mt][nt], 0, 0, 0);
    }
}

// Transpose-stage fp16 source rows [k][128 w] (row k at src + k*row_stride) into
// swizzled LDS [n=w][K], K in {64,128}.
__device__ __forceinline__ void stage_transB(const _Float16* __restrict__ src, int row_stride,
                                             _Float16* l, int K, int nblocks, int tid) {
    for (int blk = tid; blk < nblocks; blk += 256) {
        int kb = blk >> 4, wb = blk & 15;
        int k0 = kb * 4, w0 = wb * 8;
        half8v r0 = *(const half8v*)(&src[(k0 + 0) * row_stride + w0]);
        half8v r1 = *(const half8v*)(&src[(k0 + 1) * row_stride + w0]);
        half8v r2 = *(const half8v*)(&src[(k0 + 2) * row_stride + w0]);
        half8v r3 = *(const half8v*)(&src[(k0 + 3) * row_stride + w0]);
#pragma unroll
        for (int dw = 0; dw < 8; ++dw) {
            int n = w0 + dw;
            half4v p = {r0[dw], r1[dw], r2[dw], r3[dw]};
            *(half4v*)(&l[sw_off(n, k0, K)]) = p;
        }
    }
}

// ---------------------------------------------------------------------------
// Step A: xd[k][b][ci][w] = sum_h D[k][h] * x[b][ci][h][w]   (w-halves)
__global__ __launch_bounds__(256) void k_dctH(const float* __restrict__ x,
                                              const _Float16* __restrict__ Dg,
                                              _Float16* __restrict__ xd) {
    __shared__ __align__(16) _Float16 lB[64 * 128];      // 16 KB
    int b = blockIdx.x >> 7, ci = (blockIdx.x >> 1) & 63, wh = blockIdx.x & 1;
    int w0g = wh * 64;
    int tid = threadIdx.x;

    // Stage x[b][ci][0..128h][w0g..w0g+64) as fp16, transposed+swizzled.
    const float* xs = x + (long)(b * 64 + ci) * 16384 + w0g;
    {
        int kb = tid >> 3, wb = tid & 7;
        int h0 = kb * 4, c0 = wb * 8;
        f32x4 f[4][2];
#pragma unroll
        for (int dh = 0; dh < 4; ++dh) {
            f[dh][0] = *(const f32x4*)(&xs[(h0 + dh) * 128 + c0]);
            f[dh][1] = *(const f32x4*)(&xs[(h0 + dh) * 128 + c0 + 4]);
        }
#pragma unroll
        for (int dw = 0; dw < 8; ++dw) {
            int n = c0 + dw;
            half4v p = {(_Float16)f[0][dw >> 2][dw & 3], (_Float16)f[1][dw >> 2][dw & 3],
                        (_Float16)f[2][dw >> 2][dw & 3], (_Float16)f[3][dw >> 2][dw & 3]};
            *(half4v*)(&lB[sw_off(n, h0, 128)]) = p;
        }
    }
    __syncthreads();

    f32x4 acc[4][2] = {};
    gemm128x64_gA(Dg, lB, acc, tid);

    int lane = tid & 63, ln = lane & 15, q = lane >> 4;
    int wave = tid >> 6, wm = wave >> 1, wn = wave & 1;
#pragma unroll
    for (int mt = 0; mt < 4; ++mt)
#pragma unroll
        for (int nt = 0; nt < 2; ++nt)
#pragma unroll
            for (int r = 0; r < 4; ++r) {
                int kk = wm * 64 + mt * 16 + q * 4 + r;
                int wcol = w0g + wn * 32 + nt * 16 + ln;
                xd[((long)(kk * 8 + b) * 64 + ci) * 128 + wcol] = (_Float16)acc[mt][nt][r];
            }
}

// ---------------------------------------------------------------------------
// Step B: per (k,b):  y2[b][co][k][w] = sum_{s=0..9} sum_{kk} WD[k][s][co][kk] * xd[k][b][ci][(w-j)&127]
// WD A-fragments read directly from global.  b-major grid: the 8 wgs sharing a
// k-tile have bids k+128*i == k (mod 8) -> same XCD -> 80 KB tile is L2-hot.
// Register prefetch (distance 1) + NO barriers in the K-loop lets the compiler
// software-pipeline loads under MFMA.
__global__ __launch_bounds__(256) void k_conv(const _Float16* __restrict__ xd,
                                              const _Float16* __restrict__ WD,
                                              _Float16* __restrict__ y2) {
    __shared__ __align__(16) _Float16 lX[128 * 64];        // [w][ci] swizzled (16 KB)
    int bid = blockIdx.x;
    int k = bid & 127, b = bid >> 7;
    int tid = threadIdx.x;
    int lane = tid & 63, wave = tid >> 6;

    const _Float16* xs = xd + (long)(k * 8 + b) * 8192;
    stage_transB(xs, 128, lX, 64, 256, tid);
    __syncthreads();     // the only barrier

    int ln = lane & 15, q = lane >> 4;
    int wm = wave >> 1, wn = wave & 1;
    f32x4 acc[4][4] = {};

    const _Float16* wkb = WD + (long)k * 40960;   // k * 10 * 4096
    int mbase = (wm * 64 + ln) * 32 + q * 8;      // A-frag offset within s-tile (+mt*512)

    // Prefetch s=0 A-fragments.
    half8v afn[4];
#pragma unroll
    for (int mt = 0; mt < 4; ++mt)
        afn[mt] = *(const half8v*)(&wkb[mbase + mt * 512]);

    for (int s = 0; s < 10; ++s) {
        half8v af[4];
#pragma unroll
        for (int mt = 0; mt < 4; ++mt) af[mt] = afn[mt];
        if (s < 9) {
            const _Float16* wt = wkb + (s + 1) * 4096;
#pragma unroll
            for (int mt = 0; mt < 4; ++mt)
                afn[mt] = *(const half8v*)(&wt[mbase + mt * 512]);
        }
        int j = s >> 1;
        int cb = (s & 1) << 2;   // ci-chunk base within K=64
        half8v bf[4];
#pragma unroll
        for (int nt = 0; nt < 4; ++nt) {
            int wcol = wn * 64 + nt * 16 + ln;
            int n = (wcol - j) & 127;
            bf[nt] = *(const half8v*)(&lX[n * 64 + (((cb + q) ^ swz(n)) << 3)]);
        }
        __builtin_amdgcn_s_setprio(1);
#pragma unroll
        for (int mt = 0; mt < 4; ++mt)
#pragma unroll
            for (int nt = 0; nt < 4; ++nt)
                acc[mt][nt] = __builtin_amdgcn_mfma_f32_16x16x32_f16(af[mt], bf[nt], acc[mt][nt], 0, 0, 0);
        __builtin_amdgcn_s_setprio(0);
    }

    // y2 layout [b][co][k][w]: idct reads become fully contiguous per (b,co).
    _Float16* yb = y2 + (long)b * 2097152 + k * 128;
#pragma unroll
    for (int mt = 0; mt < 4; ++mt)
#pragma unroll
        for (int nt = 0; nt < 4; ++nt)
#pragma unroll
            for (int r = 0; r < 4; ++r) {
                int co = wm * 64 + mt * 16 + q * 4 + r;
                int wcol = wn * 64 + nt * 16 + ln;
                yb[(long)co * 16384 + wcol] = (_Float16)acc[mt][nt][r];
            }
}

// ---------------------------------------------------------------------------
// Step C: out[b][co][h][w] = sum_k M[h][k] * y2[b][co][k][w] + bias[co]
__global__ __launch_bounds__(256) void k_idct(const _Float16* __restrict__ y2,
                                              const _Float16* __restrict__ Mg,
                                              const float* __restrict__ bias,
                                              float* __restrict__ out) {
    __shared__ __align__(16) _Float16 lB[128 * 128];     // 32 KB
    int b = blockIdx.x >> 7, co = blockIdx.x & 127;
    int tid = threadIdx.x;

    // Contiguous 32 KB [k][w] block per (b,co).
    const _Float16* src = y2 + (long)b * 2097152 + (long)co * 16384;
    stage_transB(src, 128, lB, 128, 512, tid);
    __syncthreads();

    f32x4 acc[4][4] = {};
    gemm128_gA(Mg, lB, acc, tid);

    float bv = bias[co];
    float* ob = out + ((long)(b * 128 + co)) * 16384;
    int lane = tid & 63, ln = lane & 15, q = lane >> 4;
    int wave = tid >> 6, wm = wave >> 1, wn = wave & 1;
#pragma unroll
    for (int mt = 0; mt < 4; ++mt)
#pragma unroll
        for (int nt = 0; nt < 4; ++nt)
#pragma unroll
            for (int r = 0; r < 4; ++r) {
                int h = wm * 64 + mt * 16 + q * 4 + r;
                int wcol = wn * 64 + nt * 16 + ln;
                ob[h * 128 + wcol] = acc[mt][nt][r] + bv;
            }
}

// ---------------------------------------------------------------------------
extern "C" void kernel_launch(void* const* d_in, const int* in_sizes, int n_in,
                              void* d_out, int out_size, void* d_ws, size_t ws_size,
                              hipStream_t stream) {
    const float* x    = (const float*)d_in[0];  // [8][64][128][128]
    const float* w    = (const float*)d_in[1];  // [128][64][5][5]
    const float* bias = (const float*)d_in[2];  // [128]
    float* out = (float*)d_out;                 // [8][128][128][128]

    char* ws = (char*)d_ws;
    _Float16* D  = (_Float16*)(ws);                                  //  32 KB
    _Float16* M  = (_Float16*)(ws + 32768);                          //  32 KB
    _Float16* WD = (_Float16*)(ws + 65536);                          //  10.0 MB
    _Float16* xd = (_Float16*)(ws + 65536 + 10485760);               //  16 MB
    _Float16* y2 = (_Float16*)(ws + 65536 + 10485760 + 16777216);    //  32 MB

    k_prep<<<dim3(256),  dim3(256), 0, stream>>>(w, WD, D, M);
    k_dctH<<<dim3(1024), dim3(256), 0, stream>>>(x, D, xd);
    k_conv<<<dim3(1024), dim3(256), 0, stream>>>(xd, WD, y2);
    k_idct<<<dim3(1024), dim3(256), 0, stream>>>(y2, M, bias, out);
}

// Round 8
// 142.494 us; speedup vs baseline: 1.0877x; 1.0301x over previous
//
#include <hip/hip_runtime.h>

// ---------------------------------------------------------------------------
// DCT-conv:  out = IDCT_H( circconv_W( DCT_H(x), DCT_H(pad(w)) ) summed over ci ) + bias
// B=8, c_in=64, c_out=128, H=W=128, kh=kw=5.
//
// Pipeline (all fp16 storage, fp32 MFMA accumulate).  R8 = exact revert to the
// best-measured configuration (R5, 143.5us):
//   k_prep : D,M matrices + WD [k][s=10][co=128][kk=32]          (256 wgs)
//   k_dctH : xd[k][b][ci][w] = D @ x[b][ci]        (512 wgs, full-width tile)
//   k_conv : y2[b][co][k][w] = sum WD * xd-shifted (1024 wgs, b-major,
//            barrier-free K-loop, WD A-frags from L2, reg prefetch dist 1)
//   k_idct : out[b][co][h][w] = M @ y2 + bias      (1024 wgs, contiguous y2)
//
// LDS swizzle g(n) = (n ^ (n>>3)) & 7 XOR'd into the k-chunk index: spreads
// both staging writes (n-stride-8 lanes) and GEMM reads (n-stride-1 lanes)
// across 8 bank-pairs (2-way = free).
// ---------------------------------------------------------------------------

using half8v = __attribute__((ext_vector_type(8))) _Float16;
using half4v = __attribute__((ext_vector_type(4))) _Float16;
using f32x4  = __attribute__((ext_vector_type(4))) float;

#define PI_F 3.14159265358979323846f

// Bank-spread function: distinct over both n-stride-1 (reads) and n-stride-8 (writes).
__device__ __forceinline__ int swz(int n) { return (n ^ (n >> 3)) & 7; }

// Swizzled LDS offset for [n][K] layouts (8-half chunks; XOR 3-bit swz into chunk idx).
__device__ __forceinline__ int sw_off(int n, int k, int K) {
    int c = k >> 3;
    return n * K + (((c ^ swz(n)) << 3) | (k & 7));
}

// ---------------------------------------------------------------------------
// k_prep: WD[((k*10+s)*128+co)*32+kk] = sum_i 2cos(pi(2i+1)k/256) * w[co][ci][i][j]
//   with j = s>>1, ci = (s&1)*32 + kk.  Also fills D/M (64 entries per wg).
__global__ __launch_bounds__(256) void k_prep(const float* __restrict__ w,
                                              _Float16* __restrict__ WD,
                                              _Float16* __restrict__ D,
                                              _Float16* __restrict__ M) {
    __shared__ float lw[1600];      // w[co][ci][i][j]  (64*5*5)
    __shared__ float lcos[320];     // 2*cos(pi(2i+1)(k0+kl)/256), [kl][i]
    int co = blockIdx.x >> 1, k0 = (blockIdx.x & 1) << 6;
    int tid = threadIdx.x;

    for (int e = tid; e < 1600; e += 256) lw[e] = w[co * 1600 + e];
    for (int e = tid; e < 320; e += 256) {
        int kl = e / 5, i = e - kl * 5;
        lcos[e] = 2.0f * cosf(PI_F * (float)((2 * i + 1) * (k0 + kl)) * (1.0f / 256.0f));
    }
    // D/M matrices: 256 wgs x 64 entries = all 16384 (k,h) pairs.
    if (tid < 64) {
        int g = blockIdx.x * 64 + tid;
        int k = g >> 7, h = g & 127;
        float ang = PI_F * (float)((2 * h + 1) * k) * (1.0f / 256.0f);
        float c = cosf(ang);
        D[k * 128 + h] = (_Float16)(2.0f * c);
        float wk = (k == 0) ? 0.5f : 1.0f;
        M[h * 128 + k] = (_Float16)(c * wk * (1.0f / 256.0f));
    }
    __syncthreads();

    for (int e = tid; e < 20480; e += 256) {
        int kk = e & 31, rest = e >> 5;
        int s = rest % 10, kl = rest / 10;
        int j = s >> 1, ci = ((s & 1) << 5) + kk;
        const float* wp = &lw[ci * 25 + j];
        const float* cp = &lcos[kl * 5];
        float acc = 0.f;
#pragma unroll
        for (int i = 0; i < 5; ++i) acc += cp[i] * wp[i * 5];
        WD[(((long)(k0 + kl) * 10 + s) * 128 + co) * 32 + kk] = (_Float16)acc;
    }
}

// ---------------------------------------------------------------------------
// GEMM core with A read directly from global (L1/L2-hot 32 KB matrix, plain
// row-major [m][K=128]) and B from swizzled LDS [n][K=128].
__device__ __forceinline__ void gemm128_gA(const _Float16* __restrict__ gA,
                                           const _Float16* lB,
                                           f32x4 acc[4][4], int tid) {
    int lane = tid & 63, ln = lane & 15, q = lane >> 4;
    int wave = tid >> 6, wm = wave >> 1, wn = wave & 1;
#pragma unroll
    for (int s = 0; s < 4; ++s) {
        half8v af[4], bf[4];
#pragma unroll
        for (int mt = 0; mt < 4; ++mt) {
            int m = wm * 64 + mt * 16 + ln;
            af[mt] = *(const half8v*)(&gA[m * 128 + (s * 4 + q) * 8]);
        }
#pragma unroll
        for (int nt = 0; nt < 4; ++nt) {
            int n = wn * 64 + nt * 16 + ln;
            bf[nt] = *(const half8v*)(&lB[n * 128 + (((s * 4 + q) ^ swz(n)) << 3)]);
        }
#pragma unroll
        for (int mt = 0; mt < 4; ++mt)
#pragma unroll
            for (int nt = 0; nt < 4; ++nt)
                acc[mt][nt] = __builtin_amdgcn_mfma_f32_16x16x32_f16(af[mt], bf[nt], acc[mt][nt], 0, 0, 0);
    }
}

// Transpose-stage fp16 source rows [k][128 w] (row k at src + k*row_stride) into
// swizzled LDS [n=w][K], K in {64,128}.
__device__ __forceinline__ void stage_transB(const _Float16* __restrict__ src, int row_stride,
                                             _Float16* l, int K, int nblocks, int tid) {
    for (int blk = tid; blk < nblocks; blk += 256) {
        int kb = blk >> 4, wb = blk & 15;
        int k0 = kb * 4, w0 = wb * 8;
        half8v r0 = *(const half8v*)(&src[(k0 + 0) * row_stride + w0]);
        half8v r1 = *(const half8v*)(&src[(k0 + 1) * row_stride + w0]);
        half8v r2 = *(const half8v*)(&src[(k0 + 2) * row_stride + w0]);
        half8v r3 = *(const half8v*)(&src[(k0 + 3) * row_stride + w0]);
#pragma unroll
        for (int dw = 0; dw < 8; ++dw) {
            int n = w0 + dw;
            half4v p = {r0[dw], r1[dw], r2[dw], r3[dw]};
            *(half4v*)(&l[sw_off(n, k0, K)]) = p;
        }
    }
}

// ---------------------------------------------------------------------------
// Step A: xd[k][b][ci][w] = sum_h D[k][h] * x[b][ci][h][w]
__global__ __launch_bounds__(256) void k_dctH(const float* __restrict__ x,
                                              const _Float16* __restrict__ Dg,
                                              _Float16* __restrict__ xd) {
    __shared__ __align__(16) _Float16 lB[128 * 128];     // 32 KB
    int b = blockIdx.x >> 6, ci = blockIdx.x & 63;
    int tid = threadIdx.x;

    const float* xs = x + (long)(b * 64 + ci) * 16384;
#pragma unroll
    for (int rep = 0; rep < 2; ++rep) {
        int blk = tid + rep * 256;
        int hb = blk >> 4, wb = blk & 15;
        int h0 = hb * 4, w0 = wb * 8;
        f32x4 f[4][2];
#pragma unroll
        for (int dh = 0; dh < 4; ++dh) {
            f[dh][0] = *(const f32x4*)(&xs[(h0 + dh) * 128 + w0]);
            f[dh][1] = *(const f32x4*)(&xs[(h0 + dh) * 128 + w0 + 4]);
        }
#pragma unroll
        for (int dw = 0; dw < 8; ++dw) {
            int n = w0 + dw;
            half4v p = {(_Float16)f[0][dw >> 2][dw & 3], (_Float16)f[1][dw >> 2][dw & 3],
                        (_Float16)f[2][dw >> 2][dw & 3], (_Float16)f[3][dw >> 2][dw & 3]};
            *(half4v*)(&lB[sw_off(n, h0, 128)]) = p;
        }
    }
    __syncthreads();

    f32x4 acc[4][4] = {};
    gemm128_gA(Dg, lB, acc, tid);

    int lane = tid & 63, ln = lane & 15, q = lane >> 4;
    int wave = tid >> 6, wm = wave >> 1, wn = wave & 1;
#pragma unroll
    for (int mt = 0; mt < 4; ++mt)
#pragma unroll
        for (int nt = 0; nt < 4; ++nt)
#pragma unroll
            for (int r = 0; r < 4; ++r) {
                int kk = wm * 64 + mt * 16 + q * 4 + r;
                int wcol = wn * 64 + nt * 16 + ln;
                xd[((long)(kk * 8 + b) * 64 + ci) * 128 + wcol] = (_Float16)acc[mt][nt][r];
            }
}

// ---------------------------------------------------------------------------
// Step B: per (k,b):  y2[b][co][k][w] = sum_{s=0..9} sum_{kk} WD[k][s][co][kk] * xd[k][b][ci][(w-j)&127]
// WD A-fragments read directly from global.  b-major grid: the 8 wgs sharing a
// k-tile have bids k+128*i == k (mod 8) -> same XCD -> 80 KB tile is L2-hot.
// Register prefetch (distance 1) + NO barriers in the K-loop lets the compiler
// software-pipeline loads under MFMA.
__global__ __launch_bounds__(256) void k_conv(const _Float16* __restrict__ xd,
                                              const _Float16* __restrict__ WD,
                                              _Float16* __restrict__ y2) {
    __shared__ __align__(16) _Float16 lX[128 * 64];        // [w][ci] swizzled (16 KB)
    int bid = blockIdx.x;
    int k = bid & 127, b = bid >> 7;
    int tid = threadIdx.x;
    int lane = tid & 63, wave = tid >> 6;

    const _Float16* xs = xd + (long)(k * 8 + b) * 8192;
    stage_transB(xs, 128, lX, 64, 256, tid);
    __syncthreads();     // the only barrier

    int ln = lane & 15, q = lane >> 4;
    int wm = wave >> 1, wn = wave & 1;
    f32x4 acc[4][4] = {};

    const _Float16* wkb = WD + (long)k * 40960;   // k * 10 * 4096
    int mbase = (wm * 64 + ln) * 32 + q * 8;      // A-frag offset within s-tile (+mt*512)

    // Prefetch s=0 A-fragments.
    half8v afn[4];
#pragma unroll
    for (int mt = 0; mt < 4; ++mt)
        afn[mt] = *(const half8v*)(&wkb[mbase + mt * 512]);

    for (int s = 0; s < 10; ++s) {
        half8v af[4];
#pragma unroll
        for (int mt = 0; mt < 4; ++mt) af[mt] = afn[mt];
        if (s < 9) {
            const _Float16* wt = wkb + (s + 1) * 4096;
#pragma unroll
            for (int mt = 0; mt < 4; ++mt)
                afn[mt] = *(const half8v*)(&wt[mbase + mt * 512]);
        }
        int j = s >> 1;
        int cb = (s & 1) << 2;   // ci-chunk base within K=64
        half8v bf[4];
#pragma unroll
        for (int nt = 0; nt < 4; ++nt) {
            int wcol = wn * 64 + nt * 16 + ln;
            int n = (wcol - j) & 127;
            bf[nt] = *(const half8v*)(&lX[n * 64 + (((cb + q) ^ swz(n)) << 3)]);
        }
        __builtin_amdgcn_s_setprio(1);
#pragma unroll
        for (int mt = 0; mt < 4; ++mt)
#pragma unroll
            for (int nt = 0; nt < 4; ++nt)
                acc[mt][nt] = __builtin_amdgcn_mfma_f32_16x16x32_f16(af[mt], bf[nt], acc[mt][nt], 0, 0, 0);
        __builtin_amdgcn_s_setprio(0);
    }

    // y2 layout [b][co][k][w]: idct reads become fully contiguous per (b,co).
    _Float16* yb = y2 + (long)b * 2097152 + k * 128;
#pragma unroll
    for (int mt = 0; mt < 4; ++mt)
#pragma unroll
        for (int nt = 0; nt < 4; ++nt)
#pragma unroll
            for (int r = 0; r < 4; ++r) {
                int co = wm * 64 + mt * 16 + q * 4 + r;
                int wcol = wn * 64 + nt * 16 + ln;
                yb[(long)co * 16384 + wcol] = (_Float16)acc[mt][nt][r];
            }
}

// ---------------------------------------------------------------------------
// Step C: out[b][co][h][w] = sum_k M[h][k] * y2[b][co][k][w] + bias[co]
__global__ __launch_bounds__(256) void k_idct(const _Float16* __restrict__ y2,
                                              const _Float16* __restrict__ Mg,
                                              const float* __restrict__ bias,
                                              float* __restrict__ out) {
    __shared__ __align__(16) _Float16 lB[128 * 128];     // 32 KB
    int b = blockIdx.x >> 7, co = blockIdx.x & 127;
    int tid = threadIdx.x;

    // Contiguous 32 KB [k][w] block per (b,co).
    const _Float16* src = y2 + (long)b * 2097152 + (long)co * 16384;
    stage_transB(src, 128, lB, 128, 512, tid);
    __syncthreads();

    f32x4 acc[4][4] = {};
    gemm128_gA(Mg, lB, acc, tid);

    float bv = bias[co];
    float* ob = out + ((long)(b * 128 + co)) * 16384;
    int lane = tid & 63, ln = lane & 15, q = lane >> 4;
    int wave = tid >> 6, wm = wave >> 1, wn = wave & 1;
#pragma unroll
    for (int mt = 0; mt < 4; ++mt)
#pragma unroll
        for (int nt = 0; nt < 4; ++nt)
#pragma unroll
            for (int r = 0; r < 4; ++r) {
                int h = wm * 64 + mt * 16 + q * 4 + r;
                int wcol = wn * 64 + nt * 16 + ln;
                ob[h * 128 + wcol] = acc[mt][nt][r] + bv;
            }
}

// ---------------------------------------------------------------------------
extern "C" void kernel_launch(void* const* d_in, const int* in_sizes, int n_in,
                              void* d_out, int out_size, void* d_ws, size_t ws_size,
                              hipStream_t stream) {
    const float* x    = (const float*)d_in[0];  // [8][64][128][128]
    const float* w    = (const float*)d_in[1];  // [128][64][5][5]
    const float* bias = (const float*)d_in[2];  // [128]
    float* out = (float*)d_out;                 // [8][128][128][128]

    char* ws = (char*)d_ws;
    _Float16* D  = (_Float16*)(ws);                                  //  32 KB
    _Float16* M  = (_Float16*)(ws + 32768);                          //  32 KB
    _Float16* WD = (_Float16*)(ws + 65536);                          //  10.0 MB
    _Float16* xd = (_Float16*)(ws + 65536 + 10485760);               //  16 MB
    _Float16* y2 = (_Float16*)(ws + 65536 + 10485760 + 16777216);    //  32 MB

    k_prep<<<dim3(256),  dim3(256), 0, stream>>>(w, WD, D, M);
    k_dctH<<<dim3(512),  dim3(256), 0, stream>>>(x, D, xd);
    k_conv<<<dim3(1024), dim3(256), 0, stream>>>(xd, WD, y2);
    k_idct<<<dim3(1024), dim3(256), 0, stream>>>(y2, M, bias, out);
}